// Round 5
// baseline (107.994 us; speedup 1.0000x reference)
//
#include <hip/hip_runtime.h>
#include <hip/hip_bf16.h>

// bottom (8,256,128,128) f32; w1 (256,1,3,3); a1,w2,b2 (256,)
// out: res (8,256,64,64) ++ pexp (8,256,64,64), f32.
// K=3 S=2 P=1 -> Ho=Wo=64.
// R5: R3's occupancy (1024-thr blocks, 64 KiB LDS, 2 blocks/CU = 32 waves/CU)
// + register prefetch across PPB=4 planes/block (16 VGPR in flight).
// Grid = 512 blocks = exactly 2 resident per CU.

#define HW 16384       // 128*128
#define N_OUT 8388608  // 8*256*64*64
#define PPB 4          // planes per block

__device__ __forceinline__ float hw_log2(float x) { return __builtin_amdgcn_logf(x); }
__device__ __forceinline__ float hw_exp2(float x) { return __builtin_amdgcn_exp2f(x); }
__device__ __forceinline__ float hw_rcp(float x)  { return __builtin_amdgcn_rcpf(x); }

__global__ __launch_bounds__(1024, 8) void fused_ppool_pipe(
    const float* __restrict__ bottom,
    const float* __restrict__ w1,   // (256,3,3)
    const float* __restrict__ a1,
    const float* __restrict__ w2,
    const float* __restrict__ b2,
    float* __restrict__ out) {
    __shared__ float plane[HW];     // 64 KiB, single buffer
    __shared__ float smax[16];

    const int t    = threadIdx.x;
    const int wid  = t >> 6;
    const int lane = t & 63;
    const int bc0  = blockIdx.x * PPB;

    // Prologue: plane 0 into registers (4 x float4 = 16 VGPR).
    float4 r[4];
    {
        const float4* s0 = reinterpret_cast<const float4*>(bottom + (size_t)bc0 * HW);
        #pragma unroll
        for (int k = 0; k < 4; ++k) r[k] = s0[t + k * 1024];
    }
    float4* pl4 = reinterpret_cast<float4*>(plane);

    for (int pi = 0; pi < PPB; ++pi) {
        const int bc = bc0 + pi;
        const int c  = bc & 255;

        __syncthreads();            // all waves done reading LDS (prev plane)

        // Drain regs -> LDS; per-thread max from registers.
        float mx = 0.f;
        #pragma unroll
        for (int k = 0; k < 4; ++k) {
            float4 v = r[k];
            pl4[t + k * 1024] = v;
            mx = fmaxf(mx, fmaxf(fmaxf(fabsf(v.x), fabsf(v.y)),
                                 fmaxf(fabsf(v.z), fabsf(v.w))));
        }

        // Prefetch next plane into registers (in flight during compute).
        if (pi + 1 < PPB) {
            const float4* sn = reinterpret_cast<const float4*>(bottom + (size_t)(bc + 1) * HW);
            #pragma unroll
            for (int k = 0; k < 4; ++k) r[k] = sn[t + k * 1024];
        }

        // Block max reduce.
        #pragma unroll
        for (int off = 32; off; off >>= 1)
            mx = fmaxf(mx, __shfl_down(mx, off, 64));
        if (lane == 0) smax[wid] = mx;
        __syncthreads();            // plane data + smax visible to all

        float m = 0.f;
        #pragma unroll
        for (int k = 0; k < 16; ++k) m = fmaxf(m, smax[k]);
        const float inv_m = hw_rcp(m + 1.0f);

        // Block-uniform channel params -> scalar loads.
        float wk[9];
        #pragma unroll
        for (int k = 0; k < 9; ++k) wk[k] = w1[c * 9 + k];
        const float slope = a1[c];
        const float ww2   = w2[c];
        const float bb2   = b2[c];

        float* outres = out + (size_t)bc * 4096;
        float* outp   = out + N_OUT + (size_t)bc * 4096;

        // 16 waves x 4 output rows each; lane = output col.
        #pragma unroll
        for (int rr = 0; rr < 4; ++rr) {
            const int ho = wid * 4 + rr;
            float xw[3][3];         // [kernel row][col: 2wo-1, 2wo, 2wo+1]
            #pragma unroll
            for (int kr = 0; kr < 3; ++kr) {
                const int hi = 2 * ho - 1 + kr;     // wave-uniform
                float x0 = 0.f, x1 = 0.f, xm = 0.f;
                if ((unsigned)hi < 128u) {
                    float2 v2 = *reinterpret_cast<const float2*>(&plane[hi * 128 + lane * 2]);
                    x0 = v2.x; x1 = v2.y;
                    xm = __shfl_up(x1, 1, 64);      // col 2wo-1
                    if (lane == 0) xm = 0.f;        // zero pad col -1
                }
                xw[kr][0] = xm; xw[kr][1] = x0; xw[kr][2] = x1;
            }

            float v = 0.f;
            #pragma unroll
            for (int kr = 0; kr < 3; ++kr)
                #pragma unroll
                for (int j = 0; j < 3; ++j)
                    v += wk[kr * 3 + j] * xw[kr][j];
            v *= inv_m;
            v = v > 0.f ? v : slope * v;            // PReLU
            float p = v * ww2 + bb2;                // 1x1 dw conv + bias
            p = fminf(fmaxf(p, 1.0f), 110.0f);      // hardtanh

            float s = 0.f;
            #pragma unroll
            for (int kr = 0; kr < 3; ++kr) {
                #pragma unroll
                for (int j = 0; j < 3; ++j) {
                    float x = fmaxf(xw[kr][j], 0.f);
                    float e = hw_exp2(p * hw_log2(x));   // x=0 -> 0
                    s += (x > 0.f) ? e : 0.f;
                }
            }
            float mp  = s * (1.0f / 9.0f) + 1e-12f;
            float res = hw_exp2(hw_log2(mp) * hw_rcp(p));

            outres[ho * 64 + lane] = res;
            outp  [ho * 64 + lane] = p;
        }
    }
}

extern "C" void kernel_launch(void* const* d_in, const int* in_sizes, int n_in,
                              void* d_out, int out_size, void* d_ws, size_t ws_size,
                              hipStream_t stream) {
    const float* bottom = (const float*)d_in[0];
    const float* w1     = (const float*)d_in[1];
    const float* a1     = (const float*)d_in[2];
    const float* w2     = (const float*)d_in[3];
    const float* b2     = (const float*)d_in[4];
    float* out = (float*)d_out;

    fused_ppool_pipe<<<2048 / PPB, 1024, 0, stream>>>(bottom, w1, a1, w2, b2, out);
}

// Round 6
// 51.625 us; speedup vs baseline: 2.0919x; 2.0919x over previous
//
#include <hip/hip_runtime.h>
#include <hip/hip_bf16.h>

// bottom (8,256,128,128) f32; w1 (256,1,3,3); a1,w2,b2 (256,)
// out: res (8,256,64,64) ++ pexp (8,256,64,64), f32.  K=3 S=2 P=1 -> 64x64.
// R6: LDS double-buffer via __builtin_amdgcn_global_load_lds (no VGPR cost).
// 256 blocks x 1024 threads, 1 block/CU, PPB=8 planes/block, 2x64KiB LDS.

#define HW 16384       // 128*128
#define N_OUT 8388608  // 8*256*64*64
#define PPB 8          // planes per block

__device__ __forceinline__ float hw_log2(float x) { return __builtin_amdgcn_logf(x); }
__device__ __forceinline__ float hw_exp2(float x) { return __builtin_amdgcn_exp2f(x); }
__device__ __forceinline__ float hw_rcp(float x)  { return __builtin_amdgcn_rcpf(x); }

// Async 16B global -> LDS copy (per-lane gsrc; LDS dest = wave base + lane*16).
__device__ __forceinline__ void async_cp16(const float4* g, float4* l) {
    __builtin_amdgcn_global_load_lds(
        (const __attribute__((address_space(1))) void*)g,
        (__attribute__((address_space(3))) void*)l, 16, 0, 0);
}

__global__ __launch_bounds__(1024) void fused_ppool_db(
    const float* __restrict__ bottom,
    const float* __restrict__ w1,   // (256,3,3)
    const float* __restrict__ a1,
    const float* __restrict__ w2,
    const float* __restrict__ b2,
    float* __restrict__ out) {
    __shared__ float buf[2][HW];    // 2 x 64 KiB
    __shared__ float smax[16];

    const int t    = threadIdx.x;
    const int wid  = t >> 6;
    const int lane = t & 63;
    const int bc0  = blockIdx.x * PPB;

    // Prologue: plane bc0 -> buf[0] (async, drained by the syncthreads).
    {
        const float4* g = reinterpret_cast<const float4*>(bottom + (size_t)bc0 * HW);
        float4* l = reinterpret_cast<float4*>(buf[0]);
        #pragma unroll
        for (int k = 0; k < 4; ++k)
            async_cp16(g + t + k * 1024, l + t + k * 1024);
    }
    __syncthreads();                // vmcnt(0): buf[0] ready

    int cur = 0;
    for (int pi = 0; pi < PPB; ++pi) {
        const int bc = bc0 + pi;
        const int c  = bc & 255;

        // ---- max pass over buf[cur] (LDS) ----
        const float4* l4 = reinterpret_cast<const float4*>(buf[cur]);
        float mx = 0.f;
        #pragma unroll
        for (int k = 0; k < 4; ++k) {
            float4 v = l4[t + k * 1024];
            mx = fmaxf(mx, fmaxf(fmaxf(fabsf(v.x), fabsf(v.y)),
                                 fmaxf(fabsf(v.z), fabsf(v.w))));
        }
        #pragma unroll
        for (int off = 32; off; off >>= 1)
            mx = fmaxf(mx, __shfl_down(mx, off, 64));
        if (lane == 0) smax[wid] = mx;
        __syncthreads();            // nothing in VMEM flight -> cheap

        float m = 0.f;
        #pragma unroll
        for (int k = 0; k < 16; ++k) m = fmaxf(m, smax[k]);
        const float inv_m = hw_rcp(m + 1.0f);

        // ---- issue async prefetch of next plane into buf[cur^1] ----
        if (pi + 1 < PPB) {
            const float4* g = reinterpret_cast<const float4*>(bottom + (size_t)(bc + 1) * HW);
            float4* l = reinterpret_cast<float4*>(buf[cur ^ 1]);
            #pragma unroll
            for (int k = 0; k < 4; ++k)
                async_cp16(g + t + k * 1024, l + t + k * 1024);
        }

        // ---- compute from buf[cur] while prefetch flies ----
        float wk[9];
        #pragma unroll
        for (int k = 0; k < 9; ++k) wk[k] = w1[c * 9 + k];
        const float slope = a1[c];
        const float ww2   = w2[c];
        const float bb2   = b2[c];

        const float* plane = buf[cur];
        float* outres = out + (size_t)bc * 4096;
        float* outp   = out + N_OUT + (size_t)bc * 4096;

        #pragma unroll
        for (int rr = 0; rr < 4; ++rr) {
            const int ho = wid * 4 + rr;    // output row; lane = output col
            float xw[3][3];                 // [kernel row][col: 2wo-1, 2wo, 2wo+1]
            #pragma unroll
            for (int kr = 0; kr < 3; ++kr) {
                const int hi = 2 * ho - 1 + kr;     // wave-uniform
                float x0 = 0.f, x1 = 0.f, xm = 0.f;
                if ((unsigned)hi < 128u) {
                    float2 v2 = *reinterpret_cast<const float2*>(&plane[hi * 128 + lane * 2]);
                    x0 = v2.x; x1 = v2.y;
                    xm = __shfl_up(x1, 1, 64);      // col 2wo-1
                    if (lane == 0) xm = 0.f;        // zero pad col -1
                }
                xw[kr][0] = xm; xw[kr][1] = x0; xw[kr][2] = x1;
            }

            float v = 0.f;
            #pragma unroll
            for (int kr = 0; kr < 3; ++kr)
                #pragma unroll
                for (int j = 0; j < 3; ++j)
                    v += wk[kr * 3 + j] * xw[kr][j];
            v *= inv_m;
            v = v > 0.f ? v : slope * v;            // PReLU
            float p = v * ww2 + bb2;                // 1x1 dw conv + bias
            p = fminf(fmaxf(p, 1.0f), 110.0f);      // hardtanh

            float s = 0.f;
            #pragma unroll
            for (int kr = 0; kr < 3; ++kr) {
                #pragma unroll
                for (int j = 0; j < 3; ++j) {
                    float x = fmaxf(xw[kr][j], 0.f);
                    float e = hw_exp2(p * hw_log2(x));   // x=0 -> 0
                    s += (x > 0.f) ? e : 0.f;
                }
            }
            float mp  = s * (1.0f / 9.0f) + 1e-12f;
            float res = hw_exp2(hw_log2(mp) * hw_rcp(p));

            outres[ho * 64 + lane] = res;
            outp  [ho * 64 + lane] = p;
        }

        __syncthreads();            // vmcnt(0): prefetch landed; LDS reads done
        cur ^= 1;
    }
}

extern "C" void kernel_launch(void* const* d_in, const int* in_sizes, int n_in,
                              void* d_out, int out_size, void* d_ws, size_t ws_size,
                              hipStream_t stream) {
    const float* bottom = (const float*)d_in[0];
    const float* w1     = (const float*)d_in[1];
    const float* a1     = (const float*)d_in[2];
    const float* w2     = (const float*)d_in[3];
    const float* b2     = (const float*)d_in[4];
    float* out = (float*)d_out;

    fused_ppool_db<<<2048 / PPB, 1024, 0, stream>>>(bottom, w1, a1, w2, b2, out);
}